// Round 14
// baseline (717.651 us; speedup 1.0000x reference)
//
#include <hip/hip_runtime.h>

#define NN 50000
#define NE 800000
#define DD 128

#define BK_SHIFT 6                 // 64 rows per bucket
#define BROWS 64
#define NBUCK 782                  // ceil(50000/64)
#define ECAP 2048                  // mean fill 1024, sigma ~32
#define CHUNK 8192
#define NCHUNK 98                  // ceil(800000/8192)
#define NCAST 391                  // seq-cast blocks (128 rows each)

// ---------------- ws layout (float units) ----------------
#define OFF_SEQB  0                // NN*DD bf16 = 12.8 MB = 3,200,000 floats
#define OFF_WB    3200000          // 128*128 bf16 = 8192 floats
#define OFF_EBIN  3208192          // NBUCK*ECAP uint2 = 3,203,072 floats
#define OFF_CUR   6411264          // NBUCK ints
#define WS_FULL_FLOATS 6412100     // ~25.6 MB

typedef short short8 __attribute__((ext_vector_type(8)));
typedef float f32x4 __attribute__((ext_vector_type(4)));
typedef unsigned int uint32x4 __attribute__((ext_vector_type(4)));

static __device__ __forceinline__ unsigned int f2bf(float x) {
    unsigned int u = __float_as_uint(x);
    return (u + 0x7fffu + ((u >> 16) & 1u)) >> 16;  // RNE
}

// ============ K1: edge scatter (blocks 0..97) || seq/W cast (rest) ============
__global__ __launch_bounds__(256) void k1_cast_scatter(
        const float* __restrict__ seq, const float* __restrict__ W,
        unsigned short* __restrict__ seqb, unsigned short* __restrict__ Wb,
        const int* __restrict__ erow, const int* __restrict__ ecol,
        const float* __restrict__ eval,
        int* __restrict__ gcur, uint2* __restrict__ ebin) {
    const int t = threadIdx.x;

    if (blockIdx.x < NCHUNK) {
        // ---- scatter: LDS hist -> global bump-reserve -> contiguous runs ----
        __shared__ int lh[NBUCK];
        for (int i = t; i < NBUCK; i += 256) lh[i] = 0;
        __syncthreads();
        const int e0 = blockIdx.x * CHUNK;
        for (int i = t; i < CHUNK; i += 256) {
            int e = e0 + i;
            if (e < NE) atomicAdd(&lh[erow[e] >> BK_SHIFT], 1);
        }
        __syncthreads();
        for (int i = t; i < NBUCK; i += 256) {
            int c = lh[i];
            lh[i] = c ? atomicAdd(&gcur[i], c) : 0;
        }
        __syncthreads();
        for (int i = t; i < CHUNK; i += 256) {
            int e = e0 + i;
            if (e < NE) {
                int r = erow[e], c = ecol[e];
                unsigned int vb = __float_as_uint(eval[e]);
                int k = r >> BK_SHIFT;
                int pos = atomicAdd(&lh[k], 1);
                if (pos < ECAP)
                    ebin[(size_t)k * ECAP + pos] =
                        make_uint2(((unsigned)r << 16) | (unsigned)c, vb);
            }
        }
        return;
    }

    // ---- cast fp32 -> bf16 (seq rows, or W for the last block) ----
    const float4* in4;
    uint4* out4;
    size_t lim;   // valid element count from base
    if (blockIdx.x < NCHUNK + NCAST) {
        const int blk = blockIdx.x - NCHUNK;
        const size_t base = (size_t)blk * 128 * DD;
        in4 = (const float4*)(seq + base);
        out4 = (uint4*)(seqb + base);
        lim = (size_t)NN * DD - base;
    } else {
        in4 = (const float4*)W;
        out4 = (uint4*)Wb;
        lim = 128 * 128;
    }
    for (int i = t; i < 2048; i += 256) {
        size_t eoff = (size_t)i * 8;
        if (eoff + 8 <= lim) {
            float4 x = in4[i * 2], y = in4[i * 2 + 1];
            uint4 p;
            p.x = f2bf(x.x) | (f2bf(x.y) << 16);
            p.y = f2bf(x.z) | (f2bf(x.w) << 16);
            p.z = f2bf(y.x) | (f2bf(y.y) << 16);
            p.w = f2bf(y.z) | (f2bf(y.w) << 16);
            out4[i] = p;
        }
    }
}

// ============ K2: fused gather-aggregate (LDS fp32) + MFMA projection ========
// One block per 64-row bucket. 512 threads = 8 waves.
// LDS: agg[64][128] fp32 (32 KB, XOR-swizzled) + Wb tile bf16 (32 KB, swizzled).
__global__ __launch_bounds__(512) void k2_fused(
        const unsigned short* __restrict__ seqb,
        const unsigned short* __restrict__ Wb,
        const uint2* __restrict__ ebin,
        const int* __restrict__ gcur,
        const float* __restrict__ bias,
        float* __restrict__ out) {
    __shared__ float agg[BROWS * DD];     // 32 KB
    __shared__ uint4 wl4[2048];           // 32 KB
    char* aggb = (char*)agg;
    char* wlds = (char*)wl4;
    const int t = threadIdx.x, k = blockIdx.x;
    const int wid = t >> 6, lane = t & 63;

    for (int i = t; i < BROWS * DD; i += 512) agg[i] = 0.f;
    {   // stage W bf16 swizzled: bf16 row = 256 B = 16 uint4. row o, seg 0..15.
        const uint4* wg = (const uint4*)Wb;
        for (int i = t; i < 2048; i += 512) {
            int o = i >> 4, seg = i & 15;
            int byte = o * 256 + seg * 16;
            *(uint4*)(wlds + (byte ^ ((o & 7) << 4))) = wg[i];
        }
    }
    __syncthreads();

    int cnt = gcur[k];
    if (cnt > ECAP) cnt = ECAP;
    const uint2* eb = ebin + (size_t)k * ECAP;
    const unsigned int* sq = (const unsigned int*)seqb;

#define EBODY(EE) do {                                                         \
        uint2 ed = eb[EE];                                                     \
        float v = __uint_as_float(ed.y);                                       \
        int row = (int)(ed.x >> 16) & (BROWS - 1);                             \
        unsigned c = ed.x & 0xffffu;                                           \
        unsigned u = sq[(size_t)c * 64 + lane];                                \
        int sw = (row * 512 + lane * 8) ^ ((row & 7) << 4);                    \
        atomicAdd((float*)(aggb + sw),     v * __uint_as_float(u << 16));      \
        atomicAdd((float*)(aggb + sw + 4), v * __uint_as_float(u & 0xffff0000u)); \
    } while (0)

    int e = wid;
    for (; e + 24 < cnt; e += 32) { EBODY(e); EBODY(e + 8); EBODY(e + 16); EBODY(e + 24); }
    for (; e < cnt; e += 8) EBODY(e);
#undef EBODY

    __syncthreads();

    // MFMA phase: wave -> rows r0..r0+16, cols c0..c0+64
    const int r0 = (wid & 3) * 16, c0 = (wid >> 2) * 64;
    const int lr = lane & 15, kg = lane >> 4;
    const int arow = r0 + lr;
    const int axor = (arow & 7) << 4;
    f32x4 acc[4] = {};

#pragma unroll
    for (int ks = 0; ks < 4; ++ks) {
        int ab = arow * 512 + ks * 128 + kg * 32;
        float4 a0 = *(float4*)(aggb + (ab ^ axor));
        float4 a1 = *(float4*)(aggb + ((ab + 16) ^ axor));
        union { uint32x4 u; short8 s; } av;
        av.u.x = f2bf(a0.x) | (f2bf(a0.y) << 16);
        av.u.y = f2bf(a0.z) | (f2bf(a0.w) << 16);
        av.u.z = f2bf(a1.x) | (f2bf(a1.y) << 16);
        av.u.w = f2bf(a1.z) | (f2bf(a1.w) << 16);
#pragma unroll
        for (int c = 0; c < 4; ++c) {
            int o = c0 + c * 16 + lr;
            short8 bv = *(short8*)(wlds + ((o * 256 + ks * 64 + kg * 16) ^ ((o & 7) << 4)));
            acc[c] = __builtin_amdgcn_mfma_f32_16x16x32_bf16(av.s, bv, acc[c], 0, 0, 0);
        }
    }

#pragma unroll
    for (int c = 0; c < 4; ++c) {
        int col = c0 + c * 16 + lr;
        float bb = bias[col];
#pragma unroll
        for (int r = 0; r < 4; ++r) {
            int n = (k << BK_SHIFT) + r0 + kg * 4 + r;
            if (n < NN)
                out[(size_t)n * DD + col] = fmaxf(acc[c][r] + bb, 0.f);
        }
    }
}

extern "C" void kernel_launch(void* const* d_in, const int* in_sizes, int n_in,
                              void* d_out, int out_size, void* d_ws, size_t ws_size,
                              hipStream_t stream) {
    const float* seq  = (const float*)d_in[0];
    const float* W    = (const float*)d_in[1];
    const float* b    = (const float*)d_in[2];
    const int*   erow = (const int*)d_in[3];
    const int*   ecol = (const int*)d_in[4];
    const float* eval = (const float*)d_in[5];
    float* out = (float*)d_out;

    float* wsf = (float*)d_ws;
    unsigned short* seqb = (unsigned short*)(wsf + OFF_SEQB);
    unsigned short* Wb   = (unsigned short*)(wsf + OFF_WB);
    uint2* ebin = (uint2*)(wsf + OFF_EBIN);
    int*   gcur = (int*)(wsf + OFF_CUR);

    hipMemsetAsync(gcur, 0, NBUCK * sizeof(int), stream);
    k1_cast_scatter<<<NCHUNK + NCAST + 1, 256, 0, stream>>>(
        seq, W, seqb, Wb, erow, ecol, eval, gcur, ebin);
    k2_fused<<<NBUCK, 512, 0, stream>>>(seqb, Wb, ebin, gcur, b, out);
}

// Round 15
// 84.702 us; speedup vs baseline: 8.4726x; 8.4726x over previous
//
#include <hip/hip_runtime.h>

#define NN 50000
#define NE 800000
#define DD 128

#define BK_SHIFT 8                 // bucket = row >> 8 (256 rows per bucket)
#define NBUCK 196
#define CHUNK 2048
#define NCHUNK 391                 // ceil(800000/2048)
#define NGB 782                    // ceil(50000/64) gemm blocks
#define ECAP 8192                  // entries per bucket region (mean 4096, sigma 64)

// ---------------- ws layout (float units) ----------------
#define OFF_H      0               // NN*DD bf16 = 3,200,000 floats
#define OFF_EBIN   3200000         // NBUCK*ECAP uint2 = 3,211,264 floats
#define OFF_EPACK  6411264         // NBUCK*ECAP uint2
#define OFF_END    9622528         // NN ints
#define OFF_CUR    9672528         // NBUCK ints
#define OFF_WB     9672724         // 128*128 bf16 = 8192 floats
#define WS_FULL_FLOATS 9680916     // ~38.7 MB

typedef short short8 __attribute__((ext_vector_type(8)));
typedef float f32x4 __attribute__((ext_vector_type(4)));
typedef unsigned int uint32x2 __attribute__((ext_vector_type(2)));

static __device__ __forceinline__ unsigned int f2bf(float x) {
    unsigned int u = __float_as_uint(x);
    return (u + 0x7fffu + ((u >> 16) & 1u)) >> 16;  // RNE
}

// ============ K1: edge scatter (blocks 0..390) || W cast (block 391) ========
__global__ __launch_bounds__(256) void k1_scatter_wcast(
        const float* __restrict__ W, unsigned short* __restrict__ Wb,
        const int* __restrict__ erow, const int* __restrict__ ecol,
        const float* __restrict__ eval,
        int* __restrict__ gcur, uint2* __restrict__ ebin) {
    const int t = threadIdx.x;

    if (blockIdx.x < NCHUNK) {
        __shared__ int lh[NBUCK];
        for (int i = t; i < NBUCK; i += 256) lh[i] = 0;
        __syncthreads();
        const int e0 = blockIdx.x * CHUNK;
        for (int i = t; i < CHUNK; i += 256) {
            int e = e0 + i;
            if (e < NE) atomicAdd(&lh[erow[e] >> BK_SHIFT], 1);
        }
        __syncthreads();
        for (int i = t; i < NBUCK; i += 256) {
            int c = lh[i];
            lh[i] = c ? atomicAdd(&gcur[i], c) : 0;   // count -> bucket-local base
        }
        __syncthreads();
        for (int i = t; i < CHUNK; i += 256) {
            int e = e0 + i;
            if (e < NE) {
                int r = erow[e], c = ecol[e];
                unsigned int vb = __float_as_uint(eval[e]);
                int k = r >> BK_SHIFT;
                int pos = atomicAdd(&lh[k], 1);
                if (pos < ECAP)
                    ebin[(size_t)k * ECAP + pos] =
                        make_uint2(((unsigned)r << 16) | (unsigned)c, vb);
            }
        }
        return;
    }

    // ---- W cast fp32 -> bf16, row-major [o][k] ----
    const float4* in4 = (const float4*)W;
    uint4* out4 = (uint4*)Wb;
    for (int i = t; i < 2048; i += 256) {
        float4 x = in4[i * 2], y = in4[i * 2 + 1];
        uint4 p;
        p.x = f2bf(x.x) | (f2bf(x.y) << 16);
        p.y = f2bf(x.z) | (f2bf(x.w) << 16);
        p.z = f2bf(y.x) | (f2bf(y.y) << 16);
        p.w = f2bf(y.z) | (f2bf(y.w) << 16);
        out4[i] = p;
    }
}

// ============ K2: csr_fill (blocks 0..195) || MFMA GEMM (blocks 196..977) ====
__global__ __launch_bounds__(256) void k2_fill_gemm(
        const float* __restrict__ seq, const unsigned short* __restrict__ Wb,
        unsigned short* __restrict__ h,
        const uint2* __restrict__ ebin, const int* __restrict__ gcur,
        int* __restrict__ endv, uint2* __restrict__ epack) {
    __shared__ uint4 lds4[3072];           // 48 KB
    char* lds = (char*)lds4;
    const int t = threadIdx.x;

    if (blockIdx.x < NBUCK) {
        // ---- csr_fill path: per-bucket hist + scan + payload reorder ----
        int* lh = (int*)lds4;
        int* lx = lh + 256;
        const int k = blockIdx.x;
        const size_t s0 = (size_t)k * ECAP;
        int cnt = gcur[k];
        if (cnt > ECAP) cnt = ECAP;
        const size_t s1 = s0 + cnt;
        const int r0 = k << BK_SHIFT;

        lh[t] = 0;
        __syncthreads();
        for (size_t e = s0 + t; e < s1; e += 256)
            atomicAdd(&lh[(ebin[e].x >> 16) & 255], 1);
        __syncthreads();

        const int myc = lh[t];
        lx[t] = myc;
        __syncthreads();
        for (int off = 1; off < 256; off <<= 1) {
            int y = (t >= off) ? lx[t - off] : 0;
            __syncthreads();
            lx[t] += y;
            __syncthreads();
        }
        const int incl = lx[t];
        const int row = r0 + t;
        if (row < NN) endv[row] = (int)s0 + incl;
        __syncthreads();
        lh[t] = (int)s0 + incl - myc;     // bump = global exclusive offset
        __syncthreads();

        for (size_t e = s0 + t; e < s1; e += 256) {
            uint2 ed = ebin[e];
            int pos = atomicAdd(&lh[(ed.x >> 16) & 255], 1);
            epack[pos] = make_uint2(ed.x & 0xffffu, ed.y);
        }
        return;
    }

    // ---- GEMM path: h[n][o] = sum_k seq[n][k]*W[o][k] ----
    const int base = (blockIdx.x - NBUCK) * 64;
#define BS_OFF 16384

    // stage Bs from pre-cast bf16 W: 2048 uint4 (row o = 16 uint4), swizzled
    {
        const uint4* wg = (const uint4*)Wb;
        for (int i = t; i < 2048; i += 256) {
            int o = i >> 4, seg = i & 15;
            int byte = o * 256 + seg * 16;
            *(uint4*)(lds + BS_OFF + (byte ^ ((o & 7) << 4))) = wg[i];
        }
    }
    // stage As: seq rows [base..base+64) fp32 -> bf16, swizzled.
    {
        const int row = t >> 2, n = base + row;
        const int c0 = (t & 3) * 4;
        const float4* Sr = (const float4*)(seq + (size_t)n * 128);
        const bool ok = (n < NN);
#pragma unroll
        for (int i = 0; i < 4; ++i) {
            int cc = c0 + i;
            float4 x = ok ? Sr[cc * 2]     : make_float4(0.f, 0.f, 0.f, 0.f);
            float4 y = ok ? Sr[cc * 2 + 1] : make_float4(0.f, 0.f, 0.f, 0.f);
            uint4 p;
            p.x = f2bf(x.x) | (f2bf(x.y) << 16);
            p.y = f2bf(x.z) | (f2bf(x.w) << 16);
            p.z = f2bf(y.x) | (f2bf(y.y) << 16);
            p.w = f2bf(y.z) | (f2bf(y.w) << 16);
            int byte = row * 256 + cc * 16;
            *(uint4*)(lds + (byte ^ ((row & 7) << 4))) = p;
        }
    }
    __syncthreads();

    const int l = t & 63, wv = t >> 6;
    const int lr = l & 15, kg = l >> 4;
    const int arow = wv * 16 + lr;
    f32x4 acc[8] = {};

#pragma unroll
    for (int ks = 0; ks < 4; ++ks) {
        const int kbyte = ks * 64 + kg * 16;
        short8 av = *(short8*)(lds + ((arow * 256 + kbyte) ^ ((arow & 7) << 4)));
#pragma unroll
        for (int c = 0; c < 8; ++c) {
            const int o = c * 16 + lr;
            short8 bv = *(short8*)(lds + BS_OFF +
                                   ((o * 256 + kbyte) ^ ((o & 7) << 4)));
            acc[c] = __builtin_amdgcn_mfma_f32_16x16x32_bf16(av, bv, acc[c], 0, 0, 0);
        }
    }

#pragma unroll
    for (int c = 0; c < 8; ++c) {
#pragma unroll
        for (int r = 0; r < 4; ++r) {
            int n = base + wv * 16 + kg * 4 + r;
            if (n < NN)
                h[(size_t)n * DD + c * 16 + lr] = (unsigned short)f2bf(acc[c][r]);
        }
    }
}

// ============ K3: gather, wave per row, 4 edge slots x 16 lanes, 4-deep ======
__global__ __launch_bounds__(256) void gather_kernel(const unsigned short* __restrict__ h,
                                                     const int* __restrict__ end,
                                                     const unsigned int* __restrict__ epack,
                                                     const float* __restrict__ b,
                                                     float* __restrict__ out) {
    const int row  = blockIdx.x * 4 + (threadIdx.x >> 6);
    const int lane = threadIdx.x & 63;
    const int slot = lane >> 4;
    const int sub  = lane & 15;
    const int begin = (row & 255) ? end[row - 1] : (row >> BK_SHIFT) * ECAP;
    const int e1 = end[row];

    float acc[8] = {0.f, 0.f, 0.f, 0.f, 0.f, 0.f, 0.f, 0.f};
    const unsigned short* hp = h + sub * 8;

#define BODY(EE) do {                                                          \
        uint32x2 cv = __builtin_nontemporal_load(                              \
            (const uint32x2*)(epack + (size_t)(EE) * 2));                      \
        float v = __uint_as_float(cv.y);                                       \
        uint4 hv = *(const uint4*)(hp + (size_t)cv.x * DD);                    \
        unsigned int uu;                                                       \
        uu = hv.x;                                                             \
        acc[0] = fmaf(v, __uint_as_float(uu << 16),          acc[0]);          \
        acc[1] = fmaf(v, __uint_as_float(uu & 0xffff0000u),  acc[1]);          \
        uu = hv.y;                                                             \
        acc[2] = fmaf(v, __uint_as_float(uu << 16),          acc[2]);          \
        acc[3] = fmaf(v, __uint_as_float(uu & 0xffff0000u),  acc[3]);          \
        uu = hv.z;                                                             \
        acc[4] = fmaf(v, __uint_as_float(uu << 16),          acc[4]);          \
        acc[5] = fmaf(v, __uint_as_float(uu & 0xffff0000u),  acc[5]);          \
        uu = hv.w;                                                             \
        acc[6] = fmaf(v, __uint_as_float(uu << 16),          acc[6]);          \
        acc[7] = fmaf(v, __uint_as_float(uu & 0xffff0000u),  acc[7]);          \
    } while (0)

    int e = begin + slot;
    for (; e + 12 < e1; e += 16) { BODY(e); BODY(e + 4); BODY(e + 8); BODY(e + 12); }
    for (; e < e1; e += 4) BODY(e);
#undef BODY

#pragma unroll
    for (int i = 0; i < 8; ++i) {
        acc[i] += __shfl_xor(acc[i], 16);
        acc[i] += __shfl_xor(acc[i], 32);
    }

    if (slot == 0) {
        const float4* b4 = (const float4*)(b + sub * 8);
        float4 b0 = b4[0], b1 = b4[1];
        f32x4 o0, o1;
        o0.x = fmaxf(acc[0] + b0.x, 0.f);
        o0.y = fmaxf(acc[1] + b0.y, 0.f);
        o0.z = fmaxf(acc[2] + b0.z, 0.f);
        o0.w = fmaxf(acc[3] + b0.w, 0.f);
        o1.x = fmaxf(acc[4] + b1.x, 0.f);
        o1.y = fmaxf(acc[5] + b1.y, 0.f);
        o1.z = fmaxf(acc[6] + b1.z, 0.f);
        o1.w = fmaxf(acc[7] + b1.w, 0.f);
        f32x4* op = (f32x4*)(out + (size_t)row * DD + sub * 8);
        __builtin_nontemporal_store(o0, op);
        __builtin_nontemporal_store(o1, op + 1);
    }
}

extern "C" void kernel_launch(void* const* d_in, const int* in_sizes, int n_in,
                              void* d_out, int out_size, void* d_ws, size_t ws_size,
                              hipStream_t stream) {
    const float* seq  = (const float*)d_in[0];
    const float* W    = (const float*)d_in[1];
    const float* b    = (const float*)d_in[2];
    const int*   erow = (const int*)d_in[3];
    const int*   ecol = (const int*)d_in[4];
    const float* eval = (const float*)d_in[5];
    float* out = (float*)d_out;

    float* wsf = (float*)d_ws;
    unsigned short* h  = (unsigned short*)(wsf + OFF_H);
    uint2* ebin  = (uint2*)(wsf + OFF_EBIN);
    uint2* epack = (uint2*)(wsf + OFF_EPACK);
    int*   endv  = (int*)(wsf + OFF_END);
    int*   gcur  = (int*)(wsf + OFF_CUR);
    unsigned short* Wb = (unsigned short*)(wsf + OFF_WB);

    hipMemsetAsync(gcur, 0, NBUCK * sizeof(int), stream);
    k1_scatter_wcast<<<NCHUNK + 1, 256, 0, stream>>>(W, Wb, erow, ecol, eval,
                                                     gcur, ebin);
    k2_fill_gemm<<<NBUCK + NGB, 256, 0, stream>>>(seq, Wb, h, ebin, gcur,
                                                  endv, epack);
    gather_kernel<<<NN / 4, 256, 0, stream>>>(h, endv, (const unsigned int*)epack,
                                              b, out);
}

// Round 16
// 82.913 us; speedup vs baseline: 8.6554x; 1.0216x over previous
//
#include <hip/hip_runtime.h>

#define NN 50000
#define NE 800000
#define DD 128

#define BK_SHIFT 8                 // bucket = row >> 8 (256 rows per bucket)
#define NBUCK 196
#define CHUNK 2048
#define NCHUNK 391                 // ceil(800000/2048)
#define NGB 782                    // ceil(50000/64) gemm blocks
#define ECAP 8192                  // entries per bucket region (mean 4096, sigma 64)

// ---------------- ws layout (float units) ----------------
#define OFF_H      0               // NN*DD bf16 = 3,200,000 floats
#define OFF_EBIN   3200000         // NBUCK*ECAP uint2 = 3,211,264 floats
#define OFF_EPACK  6411264         // NBUCK*ECAP uint (4B records) = 1,605,632
#define OFF_END    8016896         // NN ints
#define OFF_CUR    8066896         // NBUCK ints
#define WS_FULL_FLOATS 8067092     // ~32.3 MB

typedef short short8 __attribute__((ext_vector_type(8)));
typedef float f32x4 __attribute__((ext_vector_type(4)));

static __device__ __forceinline__ unsigned int f2bf(float x) {
    unsigned int u = __float_as_uint(x);
    return (u + 0x7fffu + ((u >> 16) & 1u)) >> 16;  // RNE
}

// ============ K1: edge scatter (blocks 0..390, first) || MFMA GEMM (rest) ====
__global__ __launch_bounds__(256) void k1_scatter_gemm(
        const float* __restrict__ seq, const float* __restrict__ W,
        unsigned short* __restrict__ h,
        const int* __restrict__ erow, const int* __restrict__ ecol,
        const float* __restrict__ eval,
        int* __restrict__ gcur, uint2* __restrict__ ebin) {
    __shared__ uint4 lds4[3072];           // 48 KB
    char* lds = (char*)lds4;
    const int t = threadIdx.x;

    if (blockIdx.x < NCHUNK) {
        // ---- scatter: LDS hist -> global bump-reserve -> contiguous runs ----
        int* lh = (int*)lds4;
        for (int i = t; i < NBUCK; i += 256) lh[i] = 0;
        __syncthreads();
        const int e0 = blockIdx.x * CHUNK;
        for (int i = t; i < CHUNK; i += 256) {
            int e = e0 + i;
            if (e < NE) atomicAdd(&lh[erow[e] >> BK_SHIFT], 1);
        }
        __syncthreads();
        for (int i = t; i < NBUCK; i += 256) {
            int c = lh[i];
            lh[i] = c ? atomicAdd(&gcur[i], c) : 0;   // count -> bucket-local base
        }
        __syncthreads();
        for (int i = t; i < CHUNK; i += 256) {
            int e = e0 + i;
            if (e < NE) {
                int r = erow[e], c = ecol[e];
                unsigned int vb = __float_as_uint(eval[e]);
                int k = r >> BK_SHIFT;
                int pos = atomicAdd(&lh[k], 1);
                if (pos < ECAP)
                    ebin[(size_t)k * ECAP + pos] =
                        make_uint2(((unsigned)r << 16) | (unsigned)c, vb);
            }
        }
        return;
    }

    // ---- GEMM path: h[n][o] = sum_k seq[n][k]*W[o][k], bf16-in fp32-acc ----
    const int base = (blockIdx.x - NCHUNK) * 64;
#define BS_OFF 16384

    // stage Bs: W[o][k] fp32 -> bf16, swizzled. thread: o=t>>1, 64 k's.
    {
        const int o = t >> 1, ksb = (t & 1) * 64;
        const float4* Wr = (const float4*)(W + o * 128 + ksb);
#pragma unroll
        for (int i = 0; i < 16; i += 2) {
            float4 x = Wr[i], y = Wr[i + 1];
            uint4 p;
            p.x = f2bf(x.x) | (f2bf(x.y) << 16);
            p.y = f2bf(x.z) | (f2bf(x.w) << 16);
            p.z = f2bf(y.x) | (f2bf(y.y) << 16);
            p.w = f2bf(y.z) | (f2bf(y.w) << 16);
            int byte = o * 256 + (ksb + i * 4) * 2;
            *(uint4*)(lds + BS_OFF + (byte ^ ((o & 7) << 4))) = p;
        }
    }
    // stage As: seq rows [base..base+64) fp32 -> bf16, swizzled.
    {
        const int row = t >> 2, n = base + row;
        const int c0 = (t & 3) * 4;
        const float4* Sr = (const float4*)(seq + (size_t)n * 128);
        const bool ok = (n < NN);
#pragma unroll
        for (int i = 0; i < 4; ++i) {
            int cc = c0 + i;
            float4 x = ok ? Sr[cc * 2]     : make_float4(0.f, 0.f, 0.f, 0.f);
            float4 y = ok ? Sr[cc * 2 + 1] : make_float4(0.f, 0.f, 0.f, 0.f);
            uint4 p;
            p.x = f2bf(x.x) | (f2bf(x.y) << 16);
            p.y = f2bf(x.z) | (f2bf(x.w) << 16);
            p.z = f2bf(y.x) | (f2bf(y.y) << 16);
            p.w = f2bf(y.z) | (f2bf(y.w) << 16);
            int byte = row * 256 + cc * 16;
            *(uint4*)(lds + (byte ^ ((row & 7) << 4))) = p;
        }
    }
    __syncthreads();

    const int l = t & 63, wv = t >> 6;
    const int lr = l & 15, kg = l >> 4;
    const int arow = wv * 16 + lr;
    f32x4 acc[8] = {};

#pragma unroll
    for (int ks = 0; ks < 4; ++ks) {
        const int kbyte = ks * 64 + kg * 16;
        short8 av = *(short8*)(lds + ((arow * 256 + kbyte) ^ ((arow & 7) << 4)));
#pragma unroll
        for (int c = 0; c < 8; ++c) {
            const int o = c * 16 + lr;
            short8 bv = *(short8*)(lds + BS_OFF +
                                   ((o * 256 + kbyte) ^ ((o & 7) << 4)));
            acc[c] = __builtin_amdgcn_mfma_f32_16x16x32_bf16(av, bv, acc[c], 0, 0, 0);
        }
    }

#pragma unroll
    for (int c = 0; c < 8; ++c) {
#pragma unroll
        for (int r = 0; r < 4; ++r) {
            int n = base + wv * 16 + kg * 4 + r;
            if (n < NN)
                h[(size_t)n * DD + c * 16 + lr] = (unsigned short)f2bf(acc[c][r]);
        }
    }
}

// ============ K2: per-bucket CSR build, 4B packed payload ============
__global__ __launch_bounds__(256) void csr_fill(const uint2* __restrict__ ebin,
                                                const int* __restrict__ gcur,
                                                int* __restrict__ endv,
                                                unsigned int* __restrict__ epack) {
    __shared__ int lh[256];
    __shared__ int lx[256];
    const int k = blockIdx.x;
    const int t = threadIdx.x;
    const size_t s0 = (size_t)k * ECAP;
    int cnt = gcur[k];
    if (cnt > ECAP) cnt = ECAP;
    const size_t s1 = s0 + cnt;
    const int r0 = k << BK_SHIFT;

    lh[t] = 0;
    __syncthreads();
    for (size_t e = s0 + t; e < s1; e += 256)
        atomicAdd(&lh[(ebin[e].x >> 16) & 255], 1);
    __syncthreads();

    const int myc = lh[t];
    lx[t] = myc;
    __syncthreads();
    for (int off = 1; off < 256; off <<= 1) {
        int y = (t >= off) ? lx[t - off] : 0;
        __syncthreads();
        lx[t] += y;
        __syncthreads();
    }
    const int incl = lx[t];
    const int row = r0 + t;
    if (row < NN) endv[row] = (int)s0 + incl;
    __syncthreads();
    lh[t] = (int)s0 + incl - myc;     // bump = global exclusive offset
    __syncthreads();

    for (size_t e = s0 + t; e < s1; e += 256) {
        uint2 ed = ebin[e];
        int pos = atomicAdd(&lh[(ed.x >> 16) & 255], 1);
        // record = (val as bf16)<<16 | col
        epack[pos] = (ed.x & 0xffffu) | (f2bf(__uint_as_float(ed.y)) << 16);
    }
}

// ============ K3: gather, wave per row, 4 edge slots x 16 lanes, 4-deep ======
__global__ __launch_bounds__(256) void gather_kernel(const unsigned short* __restrict__ h,
                                                     const int* __restrict__ end,
                                                     const unsigned int* __restrict__ epack,
                                                     const float* __restrict__ b,
                                                     float* __restrict__ out) {
    const int row  = blockIdx.x * 4 + (threadIdx.x >> 6);
    const int lane = threadIdx.x & 63;
    const int slot = lane >> 4;
    const int sub  = lane & 15;
    const int begin = (row & 255) ? end[row - 1] : (row >> BK_SHIFT) * ECAP;
    const int e1 = end[row];

    float acc[8] = {0.f, 0.f, 0.f, 0.f, 0.f, 0.f, 0.f, 0.f};
    const unsigned short* hp = h + sub * 8;

#define BODY(EE) do {                                                          \
        unsigned int cv = __builtin_nontemporal_load(epack + (EE));            \
        float v = __uint_as_float(cv & 0xffff0000u);                           \
        uint4 hv = *(const uint4*)(hp + (size_t)(cv & 0xffffu) * DD);          \
        unsigned int uu;                                                       \
        uu = hv.x;                                                             \
        acc[0] = fmaf(v, __uint_as_float(uu << 16),          acc[0]);          \
        acc[1] = fmaf(v, __uint_as_float(uu & 0xffff0000u),  acc[1]);          \
        uu = hv.y;                                                             \
        acc[2] = fmaf(v, __uint_as_float(uu << 16),          acc[2]);          \
        acc[3] = fmaf(v, __uint_as_float(uu & 0xffff0000u),  acc[3]);          \
        uu = hv.z;                                                             \
        acc[4] = fmaf(v, __uint_as_float(uu << 16),          acc[4]);          \
        acc[5] = fmaf(v, __uint_as_float(uu & 0xffff0000u),  acc[5]);          \
        uu = hv.w;                                                             \
        acc[6] = fmaf(v, __uint_as_float(uu << 16),          acc[6]);          \
        acc[7] = fmaf(v, __uint_as_float(uu & 0xffff0000u),  acc[7]);          \
    } while (0)

    int e = begin + slot;
    for (; e + 12 < e1; e += 16) { BODY(e); BODY(e + 4); BODY(e + 8); BODY(e + 12); }
    for (; e < e1; e += 4) BODY(e);
#undef BODY

#pragma unroll
    for (int i = 0; i < 8; ++i) {
        acc[i] += __shfl_xor(acc[i], 16);
        acc[i] += __shfl_xor(acc[i], 32);
    }

    if (slot == 0) {
        const float4* b4 = (const float4*)(b + sub * 8);
        float4 b0 = b4[0], b1 = b4[1];
        f32x4 o0, o1;
        o0.x = fmaxf(acc[0] + b0.x, 0.f);
        o0.y = fmaxf(acc[1] + b0.y, 0.f);
        o0.z = fmaxf(acc[2] + b0.z, 0.f);
        o0.w = fmaxf(acc[3] + b0.w, 0.f);
        o1.x = fmaxf(acc[4] + b1.x, 0.f);
        o1.y = fmaxf(acc[5] + b1.y, 0.f);
        o1.z = fmaxf(acc[6] + b1.z, 0.f);
        o1.w = fmaxf(acc[7] + b1.w, 0.f);
        f32x4* op = (f32x4*)(out + (size_t)row * DD + sub * 8);
        __builtin_nontemporal_store(o0, op);
        __builtin_nontemporal_store(o1, op + 1);
    }
}

extern "C" void kernel_launch(void* const* d_in, const int* in_sizes, int n_in,
                              void* d_out, int out_size, void* d_ws, size_t ws_size,
                              hipStream_t stream) {
    const float* seq  = (const float*)d_in[0];
    const float* W    = (const float*)d_in[1];
    const float* b    = (const float*)d_in[2];
    const int*   erow = (const int*)d_in[3];
    const int*   ecol = (const int*)d_in[4];
    const float* eval = (const float*)d_in[5];
    float* out = (float*)d_out;

    float* wsf = (float*)d_ws;
    unsigned short* h  = (unsigned short*)(wsf + OFF_H);
    uint2* ebin  = (uint2*)(wsf + OFF_EBIN);
    unsigned int* epack = (unsigned int*)(wsf + OFF_EPACK);
    int*   endv  = (int*)(wsf + OFF_END);
    int*   gcur  = (int*)(wsf + OFF_CUR);

    hipMemsetAsync(gcur, 0, NBUCK * sizeof(int), stream);
    k1_scatter_gemm<<<NCHUNK + NGB, 256, 0, stream>>>(seq, W, h, erow, ecol,
                                                      eval, gcur, ebin);
    csr_fill<<<NBUCK, 256, 0, stream>>>(ebin, gcur, endv, epack);
    gather_kernel<<<NN / 4, 256, 0, stream>>>(h, endv, epack, b, out);
}